// Round 1
// baseline (2890.837 us; speedup 1.0000x reference)
//
#include <hip/hip_runtime.h>

// LightGCN: out = (x0 + A x0 + A^2 x0 + A^3 x0) / 4, A = COO sparse (4M nnz), D=64.
// Scheme: per-edge wave (64 lanes = 64 dims), gather x[col], fp32 atomic scatter to y[row].
// ws layout: wsA = x buffer (N*D fp32), wsB = y buffer (N*D fp32). acc lives in d_out.

#define NUSERS 200000
#define NITEMS 100000
#define NNODES 300000
#define DIM 64
#define NNZ_CNT 4000000

__global__ void k_init(const float* __restrict__ ue, const float* __restrict__ ie,
                       float* __restrict__ x, float* __restrict__ acc) {
    int i = blockIdx.x * blockDim.x + threadIdx.x;      // float4 index
    const int total = NNODES * DIM / 4;                 // 4.8M
    if (i >= total) return;
    const int userEnd = NUSERS * DIM / 4;               // 3.2M
    float4 v = (i < userEnd) ? ((const float4*)ue)[i]
                             : ((const float4*)ie)[i - userEnd];
    ((float4*)x)[i] = v;
    ((float4*)acc)[i] = v;
}

__global__ void k_spmm(const int* __restrict__ rows, const int* __restrict__ cols,
                       const float* __restrict__ vals, const float* __restrict__ x,
                       float* __restrict__ y) {
    int e = blockIdx.x * (blockDim.x >> 6) + (threadIdx.x >> 6); // one wave per edge
    int lane = threadIdx.x & 63;
    if (e >= NNZ_CNT) return;
    int r = rows[e];
    int c = cols[e];
    float v = vals[e];
    float g = v * x[c * DIM + lane];
    unsafeAtomicAdd(&y[r * DIM + lane], g);   // global_atomic_add_f32
}

// acc += y; xold = 0 (xold becomes next layer's atomic target)
__global__ void k_addzero(float* __restrict__ acc, const float* __restrict__ y,
                          float* __restrict__ xold) {
    int i = blockIdx.x * blockDim.x + threadIdx.x;
    const int total = NNODES * DIM / 4;
    if (i >= total) return;
    float4 a = ((float4*)acc)[i];
    float4 b = ((const float4*)y)[i];
    a.x += b.x; a.y += b.y; a.z += b.z; a.w += b.w;
    ((float4*)acc)[i] = a;
    ((float4*)xold)[i] = make_float4(0.f, 0.f, 0.f, 0.f);
}

// out = (acc + y) * 0.25
__global__ void k_final(float* __restrict__ acc, const float* __restrict__ y) {
    int i = blockIdx.x * blockDim.x + threadIdx.x;
    const int total = NNODES * DIM / 4;
    if (i >= total) return;
    float4 a = ((float4*)acc)[i];
    float4 b = ((const float4*)y)[i];
    a.x = (a.x + b.x) * 0.25f;
    a.y = (a.y + b.y) * 0.25f;
    a.z = (a.z + b.z) * 0.25f;
    a.w = (a.w + b.w) * 0.25f;
    ((float4*)acc)[i] = a;
}

extern "C" void kernel_launch(void* const* d_in, const int* in_sizes, int n_in,
                              void* d_out, int out_size, void* d_ws, size_t ws_size,
                              hipStream_t stream) {
    const float* ue   = (const float*)d_in[0];
    const float* ie   = (const float*)d_in[1];
    const int*   rows = (const int*)d_in[2];
    const int*   cols = (const int*)d_in[3];
    const float* vals = (const float*)d_in[4];
    float* acc = (float*)d_out;

    float* wsA = (float*)d_ws;                 // x buffer
    float* wsB = wsA + (size_t)NNODES * DIM;   // y buffer

    const int vec_total  = NNODES * DIM / 4;
    const int vec_blocks = (vec_total + 255) / 256;
    const int spmm_blocks = (NNZ_CNT + 3) / 4; // 4 waves (edges) per 256-thread block

    // x0 -> wsA, acc -> d_out; zero wsB (layer-1 atomic target)
    k_init<<<vec_blocks, 256, 0, stream>>>(ue, ie, wsA, acc);
    hipMemsetAsync(wsB, 0, (size_t)NNODES * DIM * sizeof(float), stream);

    // layer 1: x1 = A x0   (wsA -> wsB)
    k_spmm<<<spmm_blocks, 256, 0, stream>>>(rows, cols, vals, wsA, wsB);
    // acc += x1; zero wsA
    k_addzero<<<vec_blocks, 256, 0, stream>>>(acc, wsB, wsA);

    // layer 2: x2 = A x1   (wsB -> wsA)
    k_spmm<<<spmm_blocks, 256, 0, stream>>>(rows, cols, vals, wsB, wsA);
    // acc += x2; zero wsB
    k_addzero<<<vec_blocks, 256, 0, stream>>>(acc, wsA, wsB);

    // layer 3: x3 = A x2   (wsA -> wsB)
    k_spmm<<<spmm_blocks, 256, 0, stream>>>(rows, cols, vals, wsA, wsB);
    // out = (acc + x3) / 4
    k_final<<<vec_blocks, 256, 0, stream>>>(acc, wsB);
}

// Round 2
// 1500.406 us; speedup vs baseline: 1.9267x; 1.9267x over previous
//
#include <hip/hip_runtime.h>

// LightGCN: out = (x0 + A x0 + A^2 x0 + A^3 x0) / 4, COO 4M nnz, N=300k, D=64.
// R2: build CSR in-launch (hist + scan + scatter), then pull-style SpMM:
// one wave per row, register accumulate, single write per row. No fp32 atomics.

#define NUSERS 200000
#define NITEMS 100000
#define NNODES 300000
#define DIM 64
#define NNZ_CNT 4000000

#define SCAN_CHUNK 1024
#define NCHUNKS ((NNODES + SCAN_CHUNK - 1) / SCAN_CHUNK)   // 293
#define CNT_PAD (NCHUNKS * SCAN_CHUNK)                     // 300032 ints (padded, zeros)

// ---------------- shared elementwise ----------------

__global__ void k_init(const float* __restrict__ ue, const float* __restrict__ ie,
                       float* __restrict__ x, float* __restrict__ acc) {
    int i = blockIdx.x * blockDim.x + threadIdx.x;      // float4 index
    const int total = NNODES * DIM / 4;
    if (i >= total) return;
    const int userEnd = NUSERS * DIM / 4;
    float4 v = (i < userEnd) ? ((const float4*)ue)[i]
                             : ((const float4*)ie)[i - userEnd];
    ((float4*)x)[i] = v;
    ((float4*)acc)[i] = v;
}

// ---------------- CSR build ----------------

__global__ void k_hist(const int* __restrict__ rows, int* __restrict__ cnt) {
    int e = blockIdx.x * blockDim.x + threadIdx.x;
    if (e >= NNZ_CNT) return;
    atomicAdd(&cnt[rows[e]], 1);
}

__global__ void k_partial(const int* __restrict__ cnt, int* __restrict__ partial) {
    int t = threadIdx.x;
    int base = blockIdx.x * SCAN_CHUNK;
    int4 c = ((const int4*)(cnt + base))[t];
    int tsum = c.x + c.y + c.z + c.w;
    __shared__ int lds[256];
    lds[t] = tsum; __syncthreads();
    for (int d = 128; d > 0; d >>= 1) {
        if (t < d) lds[t] += lds[t + d];
        __syncthreads();
    }
    if (t == 0) partial[blockIdx.x] = lds[0];
}

__global__ void k_scanpartial(const int* __restrict__ partial, int* __restrict__ partoff) {
    int t = threadIdx.x;                     // 512 threads
    int v = (t < NCHUNKS) ? partial[t] : 0;
    __shared__ int lds[512];
    lds[t] = v; __syncthreads();
    for (int d = 1; d < 512; d <<= 1) {
        int cur = lds[t];
        int add = (t >= d) ? lds[t - d] : 0;
        __syncthreads();
        lds[t] = cur + add;
        __syncthreads();
    }
    if (t < NCHUNKS) partoff[t] = lds[t] - v;   // exclusive
}

__global__ void k_scan3(const int* __restrict__ cnt, const int* __restrict__ partoff,
                        int* __restrict__ rowptr, int* __restrict__ cursor) {
    int t = threadIdx.x, b = blockIdx.x;
    int base = b * SCAN_CHUNK;
    int4 c = ((const int4*)(cnt + base))[t];
    int tsum = c.x + c.y + c.z + c.w;
    __shared__ int lds[256];
    lds[t] = tsum; __syncthreads();
    for (int d = 1; d < 256; d <<= 1) {
        int cur = lds[t];
        int add = (t >= d) ? lds[t - d] : 0;
        __syncthreads();
        lds[t] = cur + add;
        __syncthreads();
    }
    int excl = lds[t] - tsum;
    int off = partoff[b] + excl;
    int idx = base + t * 4;
    int r0 = off, r1 = r0 + c.x, r2 = r1 + c.y, r3 = r2 + c.z;
    // regions padded to CNT_PAD(+pad) ints; writes past NNODES are harmless,
    // and rowptr[NNODES] = NNZ emerges naturally from zero-padded cnt.
    rowptr[idx + 0] = r0; rowptr[idx + 1] = r1;
    rowptr[idx + 2] = r2; rowptr[idx + 3] = r3;
    cursor[idx + 0] = r0; cursor[idx + 1] = r1;
    cursor[idx + 2] = r2; cursor[idx + 3] = r3;
}

__global__ void k_scatter(const int* __restrict__ rows, const int* __restrict__ cols,
                          const float* __restrict__ vals, int* __restrict__ cursor,
                          int2* __restrict__ packed) {
    int e = blockIdx.x * blockDim.x + threadIdx.x;
    if (e >= NNZ_CNT) return;
    int r = rows[e];
    int pos = atomicAdd(&cursor[r], 1);
    int2 p; p.x = cols[e]; p.y = __float_as_int(vals[e]);
    packed[pos] = p;
}

// ---------------- CSR SpMM: one wave per row ----------------

template <int FINAL>
__global__ void k_spmm_csr(const int* __restrict__ rowptr, const int2* __restrict__ packed,
                           const float* __restrict__ x, float* __restrict__ y,
                           float* __restrict__ acc) {
    int row  = blockIdx.x * (blockDim.x >> 6) + (threadIdx.x >> 6);
    int lane = threadIdx.x & 63;
    if (row >= NNODES) return;
    int start = rowptr[row];
    int end   = rowptr[row + 1];
    float s = 0.f;
    for (int base = start; base < end; base += 64) {
        int idx = base + lane;
        int2 cv = (idx < end) ? packed[idx] : make_int2(0, 0);
        int cnt = min(end - base, 64);
        for (int j = 0; j < cnt; ++j) {
            int   cj = __shfl(cv.x, j);
            float vj = __int_as_float(__shfl(cv.y, j));
            s += vj * x[(size_t)cj * DIM + lane];
        }
    }
    size_t o = (size_t)row * DIM + lane;
    if (FINAL) {
        acc[o] = (acc[o] + s) * 0.25f;
    } else {
        y[o] = s;
        acc[o] += s;
    }
}

// ---------------- fallback (round-1 atomic path) ----------------

__global__ void k_spmm_atomic(const int* __restrict__ rows, const int* __restrict__ cols,
                              const float* __restrict__ vals, const float* __restrict__ x,
                              float* __restrict__ y) {
    int e = blockIdx.x * (blockDim.x >> 6) + (threadIdx.x >> 6);
    int lane = threadIdx.x & 63;
    if (e >= NNZ_CNT) return;
    int r = rows[e], c = cols[e];
    float v = vals[e];
    unsafeAtomicAdd(&y[(size_t)r * DIM + lane], v * x[(size_t)c * DIM + lane]);
}

__global__ void k_addzero(float* __restrict__ acc, const float* __restrict__ y,
                          float* __restrict__ xold) {
    int i = blockIdx.x * blockDim.x + threadIdx.x;
    const int total = NNODES * DIM / 4;
    if (i >= total) return;
    float4 a = ((float4*)acc)[i];
    float4 b = ((const float4*)y)[i];
    a.x += b.x; a.y += b.y; a.z += b.z; a.w += b.w;
    ((float4*)acc)[i] = a;
    ((float4*)xold)[i] = make_float4(0.f, 0.f, 0.f, 0.f);
}

__global__ void k_final(float* __restrict__ acc, const float* __restrict__ y) {
    int i = blockIdx.x * blockDim.x + threadIdx.x;
    const int total = NNODES * DIM / 4;
    if (i >= total) return;
    float4 a = ((float4*)acc)[i];
    float4 b = ((const float4*)y)[i];
    a.x = (a.x + b.x) * 0.25f; a.y = (a.y + b.y) * 0.25f;
    a.z = (a.z + b.z) * 0.25f; a.w = (a.w + b.w) * 0.25f;
    ((float4*)acc)[i] = a;
}

// ---------------- launch ----------------

extern "C" void kernel_launch(void* const* d_in, const int* in_sizes, int n_in,
                              void* d_out, int out_size, void* d_ws, size_t ws_size,
                              hipStream_t stream) {
    const float* ue   = (const float*)d_in[0];
    const float* ie   = (const float*)d_in[1];
    const int*   rows = (const int*)d_in[2];
    const int*   cols = (const int*)d_in[3];
    const float* vals = (const float*)d_in[4];
    float* acc = (float*)d_out;

    const size_t embN = (size_t)NNODES * DIM;            // 19.2M floats
    char* p = (char*)d_ws;
    float* wsX    = (float*)p;            p += embN * sizeof(float);          // 76.8 MB
    float* wsY    = (float*)p;            p += embN * sizeof(float);          // 76.8 MB
    int*   rowptr = (int*)p;              p += (size_t)(CNT_PAD + 16) * 4;    // 1.2 MB
    int*   cnt    = (int*)p;              p += (size_t)(CNT_PAD + 16) * 4;    // 1.2 MB (hist, then cursor)
    int*   part   = (int*)p;              p += 512 * 4;
    int*   poff   = (int*)p;              p += 512 * 4;
    int2*  packed = (int2*)p;             p += (size_t)NNZ_CNT * 8;           // 32 MB
    size_t need = (size_t)(p - (char*)d_ws);

    const int vec_total  = NNODES * DIM / 4;
    const int vec_blocks = (vec_total + 255) / 256;
    const int edge_blocks = (NNZ_CNT + 255) / 256;

    if (ws_size >= need) {
        // x0 -> wsX, acc -> d_out
        k_init<<<vec_blocks, 256, 0, stream>>>(ue, ie, wsX, acc);

        // --- CSR build ---
        hipMemsetAsync(cnt, 0, (size_t)(CNT_PAD + 16) * 4, stream);
        k_hist<<<edge_blocks, 256, 0, stream>>>(rows, cnt);
        k_partial<<<NCHUNKS, 256, 0, stream>>>(cnt, part);
        k_scanpartial<<<1, 512, 0, stream>>>(part, poff);
        k_scan3<<<NCHUNKS, 256, 0, stream>>>(cnt, poff, rowptr, cnt /*cursor*/);
        k_scatter<<<edge_blocks, 256, 0, stream>>>(rows, cols, vals, cnt, packed);

        // --- 3 layers, acc fused, /4 fused into last ---
        const int row_blocks = (NNODES + 3) / 4;         // 4 waves/block
        k_spmm_csr<0><<<row_blocks, 256, 0, stream>>>(rowptr, packed, wsX, wsY, acc);
        k_spmm_csr<0><<<row_blocks, 256, 0, stream>>>(rowptr, packed, wsY, wsX, acc);
        k_spmm_csr<1><<<row_blocks, 256, 0, stream>>>(rowptr, packed, wsX, wsY, acc);
    } else {
        // fallback: round-1 atomic path (needs 153.6 MB)
        const int spmm_blocks = (NNZ_CNT + 3) / 4;
        k_init<<<vec_blocks, 256, 0, stream>>>(ue, ie, wsX, acc);
        hipMemsetAsync(wsY, 0, embN * sizeof(float), stream);
        k_spmm_atomic<<<spmm_blocks, 256, 0, stream>>>(rows, cols, vals, wsX, wsY);
        k_addzero<<<vec_blocks, 256, 0, stream>>>(acc, wsY, wsX);
        k_spmm_atomic<<<spmm_blocks, 256, 0, stream>>>(rows, cols, vals, wsY, wsX);
        k_addzero<<<vec_blocks, 256, 0, stream>>>(acc, wsX, wsY);
        k_spmm_atomic<<<spmm_blocks, 256, 0, stream>>>(rows, cols, vals, wsX, wsY);
        k_final<<<vec_blocks, 256, 0, stream>>>(acc, wsY);
    }
}

// Round 3
// 1046.472 us; speedup vs baseline: 2.7625x; 1.4338x over previous
//
#include <hip/hip_runtime.h>

// LightGCN: out = (x0 + A x0 + A^2 x0 + A^3 x0) / 4, COO 4M nnz, N=300k, D=64.
// R3: CSR build (hist+scan+scatter) as R2; SpMM pull-style one-wave-per-row with
// x4-unrolled inner loop (4 independent gathers in flight) and layer-1 fused
// concat-gather + acc init (k_init eliminated).

#define NUSERS 200000
#define NITEMS 100000
#define NNODES 300000
#define DIM 64
#define NNZ_CNT 4000000

#define SCAN_CHUNK 1024
#define NCHUNKS ((NNODES + SCAN_CHUNK - 1) / SCAN_CHUNK)   // 293
#define CNT_PAD (NCHUNKS * SCAN_CHUNK)                     // 300032 ints (padded, zeros)

// ---------------- CSR build ----------------

__global__ void k_hist(const int* __restrict__ rows, int* __restrict__ cnt) {
    int e = blockIdx.x * blockDim.x + threadIdx.x;
    if (e >= NNZ_CNT) return;
    atomicAdd(&cnt[rows[e]], 1);
}

__global__ void k_partial(const int* __restrict__ cnt, int* __restrict__ partial) {
    int t = threadIdx.x;
    int base = blockIdx.x * SCAN_CHUNK;
    int4 c = ((const int4*)(cnt + base))[t];
    int tsum = c.x + c.y + c.z + c.w;
    __shared__ int lds[256];
    lds[t] = tsum; __syncthreads();
    for (int d = 128; d > 0; d >>= 1) {
        if (t < d) lds[t] += lds[t + d];
        __syncthreads();
    }
    if (t == 0) partial[blockIdx.x] = lds[0];
}

__global__ void k_scanpartial(const int* __restrict__ partial, int* __restrict__ partoff) {
    int t = threadIdx.x;                     // 512 threads
    int v = (t < NCHUNKS) ? partial[t] : 0;
    __shared__ int lds[512];
    lds[t] = v; __syncthreads();
    for (int d = 1; d < 512; d <<= 1) {
        int cur = lds[t];
        int add = (t >= d) ? lds[t - d] : 0;
        __syncthreads();
        lds[t] = cur + add;
        __syncthreads();
    }
    if (t < NCHUNKS) partoff[t] = lds[t] - v;   // exclusive
}

__global__ void k_scan3(const int* __restrict__ cnt, const int* __restrict__ partoff,
                        int* __restrict__ rowptr, int* __restrict__ cursor) {
    int t = threadIdx.x, b = blockIdx.x;
    int base = b * SCAN_CHUNK;
    int4 c = ((const int4*)(cnt + base))[t];
    int tsum = c.x + c.y + c.z + c.w;
    __shared__ int lds[256];
    lds[t] = tsum; __syncthreads();
    for (int d = 1; d < 256; d <<= 1) {
        int cur = lds[t];
        int add = (t >= d) ? lds[t - d] : 0;
        __syncthreads();
        lds[t] = cur + add;
        __syncthreads();
    }
    int excl = lds[t] - tsum;
    int off = partoff[b] + excl;
    int idx = base + t * 4;
    int r0 = off, r1 = r0 + c.x, r2 = r1 + c.y, r3 = r2 + c.z;
    rowptr[idx + 0] = r0; rowptr[idx + 1] = r1;
    rowptr[idx + 2] = r2; rowptr[idx + 3] = r3;
    cursor[idx + 0] = r0; cursor[idx + 1] = r1;
    cursor[idx + 2] = r2; cursor[idx + 3] = r3;
}

__global__ void k_scatter(const int* __restrict__ rows, const int* __restrict__ cols,
                          const float* __restrict__ vals, int* __restrict__ cursor,
                          int2* __restrict__ packed) {
    int e = blockIdx.x * blockDim.x + threadIdx.x;
    if (e >= NNZ_CNT) return;
    int r = rows[e];
    int pos = atomicAdd(&cursor[r], 1);
    int2 p; p.x = cols[e]; p.y = __float_as_int(vals[e]);
    packed[pos] = p;
}

// ---------------- CSR SpMM: one wave per row, x4 unrolled ----------------

__device__ __forceinline__ const float* x0_ptr(int c, const float* ue, const float* ie) {
    return (c < NUSERS) ? (ue + (size_t)c * DIM) : (ie + (size_t)(c - NUSERS) * DIM);
}

// LAYER: 1 = gather from concat(ue,ie), write y + acc=x0+s
//        2 = gather x, write y + acc+=s
//        3 = gather x, write acc=(acc+s)*0.25
template <int LAYER>
__global__ void k_spmm_csr(const int* __restrict__ rowptr, const int2* __restrict__ packed,
                           const float* __restrict__ x,
                           const float* __restrict__ ue, const float* __restrict__ ie,
                           float* __restrict__ y, float* __restrict__ acc) {
    int row  = blockIdx.x * (blockDim.x >> 6) + (threadIdx.x >> 6);
    int lane = threadIdx.x & 63;
    if (row >= NNODES) return;
    int start = rowptr[row];
    int end   = rowptr[row + 1];
    float s0 = 0.f, s1 = 0.f, s2 = 0.f, s3 = 0.f;
    for (int base = start; base < end; base += 64) {
        int idx = base + lane;
        int2 cv = (idx < end) ? packed[idx] : make_int2(0, 0);
        int cnt = min(end - base, 64);
        int j = 0;
        for (; j + 4 <= cnt; j += 4) {
            int c0 = __shfl(cv.x, j + 0);
            int c1 = __shfl(cv.x, j + 1);
            int c2 = __shfl(cv.x, j + 2);
            int c3 = __shfl(cv.x, j + 3);
            float v0 = __int_as_float(__shfl(cv.y, j + 0));
            float v1 = __int_as_float(__shfl(cv.y, j + 1));
            float v2 = __int_as_float(__shfl(cv.y, j + 2));
            float v3 = __int_as_float(__shfl(cv.y, j + 3));
            const float *p0, *p1, *p2, *p3;
            if (LAYER == 1) {
                p0 = x0_ptr(c0, ue, ie); p1 = x0_ptr(c1, ue, ie);
                p2 = x0_ptr(c2, ue, ie); p3 = x0_ptr(c3, ue, ie);
            } else {
                p0 = x + (size_t)c0 * DIM; p1 = x + (size_t)c1 * DIM;
                p2 = x + (size_t)c2 * DIM; p3 = x + (size_t)c3 * DIM;
            }
            float g0 = p0[lane], g1 = p1[lane], g2 = p2[lane], g3 = p3[lane];
            s0 += v0 * g0; s1 += v1 * g1; s2 += v2 * g2; s3 += v3 * g3;
        }
        for (; j < cnt; ++j) {
            int   cj = __shfl(cv.x, j);
            float vj = __int_as_float(__shfl(cv.y, j));
            const float* pj = (LAYER == 1) ? x0_ptr(cj, ue, ie) : (x + (size_t)cj * DIM);
            s0 += vj * pj[lane];
        }
    }
    float s = (s0 + s1) + (s2 + s3);
    size_t o = (size_t)row * DIM + lane;
    if (LAYER == 1) {
        float x0v = (row < NUSERS) ? ue[(size_t)row * DIM + lane]
                                   : ie[(size_t)(row - NUSERS) * DIM + lane];
        y[o] = s;
        acc[o] = x0v + s;
    } else if (LAYER == 2) {
        y[o] = s;
        acc[o] += s;
    } else {
        acc[o] = (acc[o] + s) * 0.25f;
    }
}

// ---------------- launch ----------------

extern "C" void kernel_launch(void* const* d_in, const int* in_sizes, int n_in,
                              void* d_out, int out_size, void* d_ws, size_t ws_size,
                              hipStream_t stream) {
    const float* ue   = (const float*)d_in[0];
    const float* ie   = (const float*)d_in[1];
    const int*   rows = (const int*)d_in[2];
    const int*   cols = (const int*)d_in[3];
    const float* vals = (const float*)d_in[4];
    float* acc = (float*)d_out;

    const size_t embN = (size_t)NNODES * DIM;            // 19.2M floats
    char* p = (char*)d_ws;
    float* wsX    = (float*)p;            p += embN * sizeof(float);          // 76.8 MB (x2)
    float* wsY    = (float*)p;            p += embN * sizeof(float);          // 76.8 MB (x1, x3)
    int*   rowptr = (int*)p;              p += (size_t)(CNT_PAD + 16) * 4;    // 1.2 MB
    int*   cnt    = (int*)p;              p += (size_t)(CNT_PAD + 16) * 4;    // 1.2 MB (hist, then cursor)
    int*   part   = (int*)p;              p += 512 * 4;
    int*   poff   = (int*)p;              p += 512 * 4;
    int2*  packed = (int2*)p;             p += (size_t)NNZ_CNT * 8;           // 32 MB

    const int edge_blocks = (NNZ_CNT + 255) / 256;
    const int row_blocks  = (NNODES + 3) / 4;            // 4 waves/block

    // --- CSR build ---
    hipMemsetAsync(cnt, 0, (size_t)(CNT_PAD + 16) * 4, stream);
    k_hist<<<edge_blocks, 256, 0, stream>>>(rows, cnt);
    k_partial<<<NCHUNKS, 256, 0, stream>>>(cnt, part);
    k_scanpartial<<<1, 512, 0, stream>>>(part, poff);
    k_scan3<<<NCHUNKS, 256, 0, stream>>>(cnt, poff, rowptr, cnt /*cursor*/);
    k_scatter<<<edge_blocks, 256, 0, stream>>>(rows, cols, vals, cnt, packed);

    // --- 3 layers, acc fused, /4 fused into last, x0 read fused into layer 1 ---
    k_spmm_csr<1><<<row_blocks, 256, 0, stream>>>(rowptr, packed, (const float*)nullptr,
                                                  ue, ie, wsY, acc);   // x1 -> wsY
    k_spmm_csr<2><<<row_blocks, 256, 0, stream>>>(rowptr, packed, wsY,
                                                  ue, ie, wsX, acc);   // x2 -> wsX
    k_spmm_csr<3><<<row_blocks, 256, 0, stream>>>(rowptr, packed, wsX,
                                                  ue, ie, wsY, acc);   // out
}

// Round 4
// 955.903 us; speedup vs baseline: 3.0242x; 1.0947x over previous
//
#include <hip/hip_runtime.h>

// LightGCN: out = (x0 + A x0 + A^2 x0 + A^3 x0) / 4, COO 4M nnz, N=300k, D=64.
// R4: CSR build = hist + scan + two-phase LDS-binned bucket sort (no 8B random
// global scatter; every write level is L2-mergeable). SpMM unchanged from R3:
// pull-style one-wave-per-row, x4-unrolled, layer-1 fused concat-gather.

#define NUSERS 200000
#define NITEMS 100000
#define NNODES 300000
#define DIM 64
#define NNZ_CNT 4000000

#define SCAN_CHUNK 1024
#define NCHUNKS ((NNODES + SCAN_CHUNK - 1) / SCAN_CHUNK)   // 293
#define CNT_PAD (NCHUNKS * SCAN_CHUNK)                     // 300032 ints (padded, zeros)

#define BSHIFT 11
#define BROWS  (1 << BSHIFT)                               // 2048 rows per bucket
#define NB     ((NNODES + BROWS - 1) >> BSHIFT)            // 147 buckets
#define EPB    8192                                        // edges per bucketA block

// ---------------- CSR build: hist + scan ----------------

__global__ void k_hist(const int* __restrict__ rows, int* __restrict__ cnt) {
    int e = blockIdx.x * blockDim.x + threadIdx.x;
    if (e >= NNZ_CNT) return;
    atomicAdd(&cnt[rows[e]], 1);
}

__global__ void k_partial(const int* __restrict__ cnt, int* __restrict__ partial) {
    int t = threadIdx.x;
    int base = blockIdx.x * SCAN_CHUNK;
    int4 c = ((const int4*)(cnt + base))[t];
    int tsum = c.x + c.y + c.z + c.w;
    __shared__ int lds[256];
    lds[t] = tsum; __syncthreads();
    for (int d = 128; d > 0; d >>= 1) {
        if (t < d) lds[t] += lds[t + d];
        __syncthreads();
    }
    if (t == 0) partial[blockIdx.x] = lds[0];
}

__global__ void k_scanpartial(const int* __restrict__ partial, int* __restrict__ partoff) {
    int t = threadIdx.x;                     // 512 threads
    int v = (t < NCHUNKS) ? partial[t] : 0;
    __shared__ int lds[512];
    lds[t] = v; __syncthreads();
    for (int d = 1; d < 512; d <<= 1) {
        int cur = lds[t];
        int add = (t >= d) ? lds[t - d] : 0;
        __syncthreads();
        lds[t] = cur + add;
        __syncthreads();
    }
    if (t < NCHUNKS) partoff[t] = lds[t] - v;   // exclusive
}

__global__ void k_scan3(const int* __restrict__ cnt, const int* __restrict__ partoff,
                        int* __restrict__ rowptr) {
    int t = threadIdx.x, b = blockIdx.x;
    int base = b * SCAN_CHUNK;
    int4 c = ((const int4*)(cnt + base))[t];
    int tsum = c.x + c.y + c.z + c.w;
    __shared__ int lds[256];
    lds[t] = tsum; __syncthreads();
    for (int d = 1; d < 256; d <<= 1) {
        int cur = lds[t];
        int add = (t >= d) ? lds[t - d] : 0;
        __syncthreads();
        lds[t] = cur + add;
        __syncthreads();
    }
    int excl = lds[t] - tsum;
    int off = partoff[b] + excl;
    int idx = base + t * 4;
    rowptr[idx + 0] = off;
    rowptr[idx + 1] = off + c.x;
    rowptr[idx + 2] = off + c.x + c.y;
    rowptr[idx + 3] = off + c.x + c.y + c.z;
    // rowptr[NNODES] = NNZ emerges from zero-padded cnt.
}

// gcursor[b] = rowptr[min(b * BROWS, NNODES)]
__global__ void k_initcur(const int* __restrict__ rowptr, int* __restrict__ gcursor) {
    int t = threadIdx.x;
    if (t >= NB) return;
    int r = t << BSHIFT;
    if (r > NNODES) r = NNODES;
    gcursor[t] = rowptr[r];
}

// ---------------- Phase A: bucket staging (LDS-binned) ----------------

__global__ void __launch_bounds__(256) k_bucketA(
        const int* __restrict__ rows, const int* __restrict__ cols,
        const float* __restrict__ vals, int* __restrict__ gcursor,
        int2* __restrict__ staged) {
    __shared__ int hist[NB];
    __shared__ int lbase[NB];
    __shared__ int lcur[NB];
    int t = threadIdx.x;
    int e0 = blockIdx.x * EPB;
    for (int i = t; i < NB; i += 256) { hist[i] = 0; lcur[i] = 0; }
    __syncthreads();
    // pass 1: local histogram
    for (int k = 0; k < EPB / 256; ++k) {
        int e = e0 + k * 256 + t;
        if (e < NNZ_CNT) atomicAdd(&hist[rows[e] >> BSHIFT], 1);
    }
    __syncthreads();
    // reserve contiguous ranges per bucket
    for (int i = t; i < NB; i += 256) {
        int h = hist[i];
        lbase[i] = h ? atomicAdd(&gcursor[i], h) : 0;
    }
    __syncthreads();
    // pass 2: place edges
    for (int k = 0; k < EPB / 256; ++k) {
        int e = e0 + k * 256 + t;
        if (e >= NNZ_CNT) continue;
        int r = rows[e];
        int b = r >> BSHIFT;
        int p = lbase[b] + atomicAdd(&lcur[b], 1);
        int2 rec;
        rec.x = ((r & (BROWS - 1)) << 19) | cols[e];   // rel_row[11] | col[19]
        rec.y = __float_as_int(vals[e]);
        staged[p] = rec;
    }
}

// ---------------- Phase B: per-bucket row sort (LDS cursors) ----------------

__global__ void __launch_bounds__(1024) k_bucketB(
        const int* __restrict__ rowptr, const int2* __restrict__ staged,
        int2* __restrict__ packed) {
    __shared__ int cur[BROWS];
    int b = blockIdx.x;
    int t = threadIdx.x;
    int r0 = b << BSHIFT;
    int r1 = min(r0 + BROWS, NNODES);
    int nrows = r1 - r0;
    for (int i = t; i < nrows; i += 1024) cur[i] = rowptr[r0 + i];
    __syncthreads();
    int start = rowptr[r0];
    int end   = rowptr[r1];
    for (int idx = start + t; idx < end; idx += 1024) {
        int2 rec = staged[idx];
        int rel = ((unsigned)rec.x) >> 19;
        int col = rec.x & 0x7FFFF;
        int pos = atomicAdd(&cur[rel], 1);
        int2 out; out.x = col; out.y = rec.y;
        packed[pos] = out;
    }
}

// ---------------- CSR SpMM: one wave per row, x4 unrolled ----------------

__device__ __forceinline__ const float* x0_ptr(int c, const float* ue, const float* ie) {
    return (c < NUSERS) ? (ue + (size_t)c * DIM) : (ie + (size_t)(c - NUSERS) * DIM);
}

// LAYER: 1 = gather from concat(ue,ie), write y + acc=x0+s
//        2 = gather x, write y + acc+=s
//        3 = gather x, write acc=(acc+s)*0.25
template <int LAYER>
__global__ void k_spmm_csr(const int* __restrict__ rowptr, const int2* __restrict__ packed,
                           const float* __restrict__ x,
                           const float* __restrict__ ue, const float* __restrict__ ie,
                           float* __restrict__ y, float* __restrict__ acc) {
    int row  = blockIdx.x * (blockDim.x >> 6) + (threadIdx.x >> 6);
    int lane = threadIdx.x & 63;
    if (row >= NNODES) return;
    int start = rowptr[row];
    int end   = rowptr[row + 1];
    float s0 = 0.f, s1 = 0.f, s2 = 0.f, s3 = 0.f;
    for (int base = start; base < end; base += 64) {
        int idx = base + lane;
        int2 cv = (idx < end) ? packed[idx] : make_int2(0, 0);
        int cnt = min(end - base, 64);
        int j = 0;
        for (; j + 4 <= cnt; j += 4) {
            int c0 = __shfl(cv.x, j + 0);
            int c1 = __shfl(cv.x, j + 1);
            int c2 = __shfl(cv.x, j + 2);
            int c3 = __shfl(cv.x, j + 3);
            float v0 = __int_as_float(__shfl(cv.y, j + 0));
            float v1 = __int_as_float(__shfl(cv.y, j + 1));
            float v2 = __int_as_float(__shfl(cv.y, j + 2));
            float v3 = __int_as_float(__shfl(cv.y, j + 3));
            const float *p0, *p1, *p2, *p3;
            if (LAYER == 1) {
                p0 = x0_ptr(c0, ue, ie); p1 = x0_ptr(c1, ue, ie);
                p2 = x0_ptr(c2, ue, ie); p3 = x0_ptr(c3, ue, ie);
            } else {
                p0 = x + (size_t)c0 * DIM; p1 = x + (size_t)c1 * DIM;
                p2 = x + (size_t)c2 * DIM; p3 = x + (size_t)c3 * DIM;
            }
            float g0 = p0[lane], g1 = p1[lane], g2 = p2[lane], g3 = p3[lane];
            s0 += v0 * g0; s1 += v1 * g1; s2 += v2 * g2; s3 += v3 * g3;
        }
        for (; j < cnt; ++j) {
            int   cj = __shfl(cv.x, j);
            float vj = __int_as_float(__shfl(cv.y, j));
            const float* pj = (LAYER == 1) ? x0_ptr(cj, ue, ie) : (x + (size_t)cj * DIM);
            s0 += vj * pj[lane];
        }
    }
    float s = (s0 + s1) + (s2 + s3);
    size_t o = (size_t)row * DIM + lane;
    if (LAYER == 1) {
        float x0v = (row < NUSERS) ? ue[(size_t)row * DIM + lane]
                                   : ie[(size_t)(row - NUSERS) * DIM + lane];
        y[o] = s;
        acc[o] = x0v + s;
    } else if (LAYER == 2) {
        y[o] = s;
        acc[o] += s;
    } else {
        acc[o] = (acc[o] + s) * 0.25f;
    }
}

// ---------------- launch ----------------

extern "C" void kernel_launch(void* const* d_in, const int* in_sizes, int n_in,
                              void* d_out, int out_size, void* d_ws, size_t ws_size,
                              hipStream_t stream) {
    const float* ue   = (const float*)d_in[0];
    const float* ie   = (const float*)d_in[1];
    const int*   rows = (const int*)d_in[2];
    const int*   cols = (const int*)d_in[3];
    const float* vals = (const float*)d_in[4];
    float* acc = (float*)d_out;

    const size_t embN = (size_t)NNODES * DIM;            // 19.2M floats
    char* p = (char*)d_ws;
    float* wsX    = (float*)p;            p += embN * sizeof(float);          // 76.8 MB (staging, then x2)
    float* wsY    = (float*)p;            p += embN * sizeof(float);          // 76.8 MB (x1, x3)
    int*   rowptr = (int*)p;              p += (size_t)(CNT_PAD + 16) * 4;    // 1.2 MB
    int*   cnt    = (int*)p;              p += (size_t)(CNT_PAD + 16) * 4;    // 1.2 MB
    int*   part   = (int*)p;              p += 512 * 4;
    int*   poff   = (int*)p;              p += 512 * 4;
    int*   gcur   = (int*)p;              p += 256 * 4;
    int2*  packed = (int2*)p;             p += (size_t)NNZ_CNT * 8;           // 32 MB

    int2* staged = (int2*)wsX;                            // 32 MB inside wsX (free until layer 2)

    const int edge_blocks = (NNZ_CNT + 255) / 256;
    const int row_blocks  = (NNODES + 3) / 4;             // 4 waves/block
    const int bucketA_blocks = (NNZ_CNT + EPB - 1) / EPB; // 489

    // --- rowptr ---
    hipMemsetAsync(cnt, 0, (size_t)(CNT_PAD + 16) * 4, stream);
    k_hist<<<edge_blocks, 256, 0, stream>>>(rows, cnt);
    k_partial<<<NCHUNKS, 256, 0, stream>>>(cnt, part);
    k_scanpartial<<<1, 512, 0, stream>>>(part, poff);
    k_scan3<<<NCHUNKS, 256, 0, stream>>>(cnt, poff, rowptr);

    // --- bucket sort: COO -> staged (bucket-major) -> packed (row-major) ---
    k_initcur<<<1, 256, 0, stream>>>(rowptr, gcur);
    k_bucketA<<<bucketA_blocks, 256, 0, stream>>>(rows, cols, vals, gcur, staged);
    k_bucketB<<<NB, 1024, 0, stream>>>(rowptr, staged, packed);

    // --- 3 layers, acc fused, /4 fused into last, x0 read fused into layer 1 ---
    k_spmm_csr<1><<<row_blocks, 256, 0, stream>>>(rowptr, packed, (const float*)nullptr,
                                                  ue, ie, wsY, acc);   // x1 -> wsY
    k_spmm_csr<2><<<row_blocks, 256, 0, stream>>>(rowptr, packed, wsY,
                                                  ue, ie, wsX, acc);   // x2 -> wsX
    k_spmm_csr<3><<<row_blocks, 256, 0, stream>>>(rowptr, packed, wsX,
                                                  ue, ie, wsY, acc);   // out
}

// Round 5
// 876.411 us; speedup vs baseline: 3.2985x; 1.0907x over previous
//
#include <hip/hip_runtime.h>

// LightGCN: out = (x0 + A x0 + A^2 x0 + A^3 x0) / 4, COO 4M nnz, N=300k, D=64.
// R5: inter-layer activations stored in bf16 (row=128B) -> per-XCD compulsory
// gather traffic halves (FETCH was ~8 XCDs x |x|). Accumulation stays fp32.
// Build pipeline as R4 (hist + scan + 2-phase bucket sort), buckets 2048->1024.

#define NUSERS 200000
#define NITEMS 100000
#define NNODES 300000
#define DIM 64
#define NNZ_CNT 4000000

#define SCAN_CHUNK 1024
#define NCHUNKS ((NNODES + SCAN_CHUNK - 1) / SCAN_CHUNK)   // 293
#define CNT_PAD (NCHUNKS * SCAN_CHUNK)                     // 300032 ints (padded, zeros)

#define BSHIFT 10
#define BROWS  (1 << BSHIFT)                               // 1024 rows per bucket
#define NB     ((NNODES + BROWS - 1) >> BSHIFT)            // 293 buckets
#define EPB    8192                                        // edges per bucketA block

// ---------------- bf16 helpers (RNE) ----------------

__device__ __forceinline__ unsigned short f32_to_bf16(float f) {
    unsigned u = __float_as_uint(f);
    u += 0x7FFFu + ((u >> 16) & 1u);
    return (unsigned short)(u >> 16);
}
__device__ __forceinline__ float bf16_to_f32(unsigned short h) {
    return __uint_as_float(((unsigned)h) << 16);
}

// ---------------- CSR build: hist + scan ----------------

__global__ void k_hist(const int* __restrict__ rows, int* __restrict__ cnt) {
    int e = blockIdx.x * blockDim.x + threadIdx.x;
    if (e >= NNZ_CNT) return;
    atomicAdd(&cnt[rows[e]], 1);
}

__global__ void k_partial(const int* __restrict__ cnt, int* __restrict__ partial) {
    int t = threadIdx.x;
    int base = blockIdx.x * SCAN_CHUNK;
    int4 c = ((const int4*)(cnt + base))[t];
    int tsum = c.x + c.y + c.z + c.w;
    __shared__ int lds[256];
    lds[t] = tsum; __syncthreads();
    for (int d = 128; d > 0; d >>= 1) {
        if (t < d) lds[t] += lds[t + d];
        __syncthreads();
    }
    if (t == 0) partial[blockIdx.x] = lds[0];
}

__global__ void k_scanpartial(const int* __restrict__ partial, int* __restrict__ partoff) {
    int t = threadIdx.x;                     // 512 threads
    int v = (t < NCHUNKS) ? partial[t] : 0;
    __shared__ int lds[512];
    lds[t] = v; __syncthreads();
    for (int d = 1; d < 512; d <<= 1) {
        int cur = lds[t];
        int add = (t >= d) ? lds[t - d] : 0;
        __syncthreads();
        lds[t] = cur + add;
        __syncthreads();
    }
    if (t < NCHUNKS) partoff[t] = lds[t] - v;   // exclusive
}

__global__ void k_scan3(const int* __restrict__ cnt, const int* __restrict__ partoff,
                        int* __restrict__ rowptr) {
    int t = threadIdx.x, b = blockIdx.x;
    int base = b * SCAN_CHUNK;
    int4 c = ((const int4*)(cnt + base))[t];
    int tsum = c.x + c.y + c.z + c.w;
    __shared__ int lds[256];
    lds[t] = tsum; __syncthreads();
    for (int d = 1; d < 256; d <<= 1) {
        int cur = lds[t];
        int add = (t >= d) ? lds[t - d] : 0;
        __syncthreads();
        lds[t] = cur + add;
        __syncthreads();
    }
    int excl = lds[t] - tsum;
    int off = partoff[b] + excl;
    int idx = base + t * 4;
    rowptr[idx + 0] = off;
    rowptr[idx + 1] = off + c.x;
    rowptr[idx + 2] = off + c.x + c.y;
    rowptr[idx + 3] = off + c.x + c.y + c.z;
    // rowptr[NNODES] = NNZ emerges from zero-padded cnt.
}

// gcursor[b] = rowptr[min(b * BROWS, NNODES)]
__global__ void k_initcur(const int* __restrict__ rowptr, int* __restrict__ gcursor) {
    int t = blockIdx.x * blockDim.x + threadIdx.x;
    if (t >= NB) return;
    int r = t << BSHIFT;
    if (r > NNODES) r = NNODES;
    gcursor[t] = rowptr[r];
}

// ---------------- Phase A: bucket staging (LDS-binned) ----------------

__global__ void __launch_bounds__(256) k_bucketA(
        const int* __restrict__ rows, const int* __restrict__ cols,
        const float* __restrict__ vals, int* __restrict__ gcursor,
        int2* __restrict__ staged) {
    __shared__ int hist[NB];
    __shared__ int lbase[NB];
    __shared__ int lcur[NB];
    int t = threadIdx.x;
    int e0 = blockIdx.x * EPB;
    for (int i = t; i < NB; i += 256) { hist[i] = 0; lcur[i] = 0; }
    __syncthreads();
    // pass 1: local histogram
    for (int k = 0; k < EPB / 256; ++k) {
        int e = e0 + k * 256 + t;
        if (e < NNZ_CNT) atomicAdd(&hist[rows[e] >> BSHIFT], 1);
    }
    __syncthreads();
    // reserve contiguous ranges per bucket
    for (int i = t; i < NB; i += 256) {
        int h = hist[i];
        lbase[i] = h ? atomicAdd(&gcursor[i], h) : 0;
    }
    __syncthreads();
    // pass 2: place edges
    for (int k = 0; k < EPB / 256; ++k) {
        int e = e0 + k * 256 + t;
        if (e >= NNZ_CNT) continue;
        int r = rows[e];
        int b = r >> BSHIFT;
        int p = lbase[b] + atomicAdd(&lcur[b], 1);
        int2 rec;
        rec.x = ((r & (BROWS - 1)) << 19) | cols[e];   // rel_row[10] | col[19]
        rec.y = __float_as_int(vals[e]);
        staged[p] = rec;
    }
}

// ---------------- Phase B: per-bucket row sort (LDS cursors) ----------------

__global__ void __launch_bounds__(1024) k_bucketB(
        const int* __restrict__ rowptr, const int2* __restrict__ staged,
        int2* __restrict__ packed) {
    __shared__ int cur[BROWS];
    int b = blockIdx.x;
    int t = threadIdx.x;
    int r0 = b << BSHIFT;
    int r1 = min(r0 + BROWS, NNODES);
    int nrows = r1 - r0;
    for (int i = t; i < nrows; i += 1024) cur[i] = rowptr[r0 + i];
    __syncthreads();
    int start = rowptr[r0];
    int end   = rowptr[r1];
    for (int idx = start + t; idx < end; idx += 1024) {
        int2 rec = staged[idx];
        int rel = ((unsigned)rec.x) >> 19;
        int col = rec.x & 0x7FFFF;
        int pos = atomicAdd(&cur[rel], 1);
        int2 out; out.x = col; out.y = rec.y;
        packed[pos] = out;
    }
}

// ---------------- x0 -> bf16 + acc init ----------------

__global__ void k_init0(const float* __restrict__ ue, const float* __restrict__ ie,
                        unsigned short* __restrict__ xb0, float* __restrict__ acc) {
    int i = blockIdx.x * blockDim.x + threadIdx.x;      // float4 index
    const int total = NNODES * DIM / 4;
    if (i >= total) return;
    const int userEnd = NUSERS * DIM / 4;
    float4 v = (i < userEnd) ? ((const float4*)ue)[i]
                             : ((const float4*)ie)[i - userEnd];
    ((float4*)acc)[i] = v;
    ushort4 h;
    h.x = f32_to_bf16(v.x); h.y = f32_to_bf16(v.y);
    h.z = f32_to_bf16(v.z); h.w = f32_to_bf16(v.w);
    ((ushort4*)xb0)[i] = h;
}

// ---------------- CSR SpMM: one wave per row, x4 unrolled, bf16 gather ----------------

// FINAL=0: y = bf16(s); acc += s       (layers 1,2; acc already holds x0+...)
// FINAL=1: acc = (acc + s) * 0.25      (layer 3)
template <int FINAL>
__global__ void k_spmm_csr(const int* __restrict__ rowptr, const int2* __restrict__ packed,
                           const unsigned short* __restrict__ xin,
                           unsigned short* __restrict__ y, float* __restrict__ acc) {
    int row  = blockIdx.x * (blockDim.x >> 6) + (threadIdx.x >> 6);
    int lane = threadIdx.x & 63;
    if (row >= NNODES) return;
    int start = rowptr[row];
    int end   = rowptr[row + 1];
    float s0 = 0.f, s1 = 0.f, s2 = 0.f, s3 = 0.f;
    for (int base = start; base < end; base += 64) {
        int idx = base + lane;
        int2 cv = (idx < end) ? packed[idx] : make_int2(0, 0);
        int cnt = min(end - base, 64);
        int j = 0;
        for (; j + 4 <= cnt; j += 4) {
            int c0 = __shfl(cv.x, j + 0);
            int c1 = __shfl(cv.x, j + 1);
            int c2 = __shfl(cv.x, j + 2);
            int c3 = __shfl(cv.x, j + 3);
            float v0 = __int_as_float(__shfl(cv.y, j + 0));
            float v1 = __int_as_float(__shfl(cv.y, j + 1));
            float v2 = __int_as_float(__shfl(cv.y, j + 2));
            float v3 = __int_as_float(__shfl(cv.y, j + 3));
            float g0 = bf16_to_f32(xin[((size_t)c0 << 6) + lane]);
            float g1 = bf16_to_f32(xin[((size_t)c1 << 6) + lane]);
            float g2 = bf16_to_f32(xin[((size_t)c2 << 6) + lane]);
            float g3 = bf16_to_f32(xin[((size_t)c3 << 6) + lane]);
            s0 += v0 * g0; s1 += v1 * g1; s2 += v2 * g2; s3 += v3 * g3;
        }
        for (; j < cnt; ++j) {
            int   cj = __shfl(cv.x, j);
            float vj = __int_as_float(__shfl(cv.y, j));
            s0 += vj * bf16_to_f32(xin[((size_t)cj << 6) + lane]);
        }
    }
    float s = (s0 + s1) + (s2 + s3);
    size_t o = ((size_t)row << 6) + lane;
    if (FINAL) {
        acc[o] = (acc[o] + s) * 0.25f;
    } else {
        y[o] = f32_to_bf16(s);
        acc[o] += s;
    }
}

// ---------------- launch ----------------

extern "C" void kernel_launch(void* const* d_in, const int* in_sizes, int n_in,
                              void* d_out, int out_size, void* d_ws, size_t ws_size,
                              hipStream_t stream) {
    const float* ue   = (const float*)d_in[0];
    const float* ie   = (const float*)d_in[1];
    const int*   rows = (const int*)d_in[2];
    const int*   cols = (const int*)d_in[3];
    const float* vals = (const float*)d_in[4];
    float* acc = (float*)d_out;

    const size_t embN = (size_t)NNODES * DIM;            // 19.2M elements
    char* p = (char*)d_ws;
    unsigned short* xb0 = (unsigned short*)p;  p += embN * 2;                 // 38.4 MB
    unsigned short* xb1 = (unsigned short*)p;  p += embN * 2;                 // 38.4 MB
    unsigned short* xb2 = (unsigned short*)p;  p += embN * 2;                 // 38.4 MB
    int*   rowptr = (int*)p;              p += (size_t)(CNT_PAD + 16) * 4;    // 1.2 MB
    int*   cnt    = (int*)p;              p += (size_t)(CNT_PAD + 16) * 4;    // 1.2 MB
    int*   part   = (int*)p;              p += 512 * 4;
    int*   poff   = (int*)p;              p += 512 * 4;
    int*   gcur   = (int*)p;              p += 512 * 4;
    int2*  staged = (int2*)p;             p += (size_t)NNZ_CNT * 8;           // 32 MB
    int2*  packed = (int2*)p;             p += (size_t)NNZ_CNT * 8;           // 32 MB

    const int edge_blocks = (NNZ_CNT + 255) / 256;
    const int row_blocks  = (NNODES + 3) / 4;             // 4 waves/block
    const int bucketA_blocks = (NNZ_CNT + EPB - 1) / EPB; // 489
    const int vec_blocks = (NNODES * DIM / 4 + 255) / 256;

    // --- rowptr ---
    hipMemsetAsync(cnt, 0, (size_t)(CNT_PAD + 16) * 4, stream);
    k_hist<<<edge_blocks, 256, 0, stream>>>(rows, cnt);
    k_partial<<<NCHUNKS, 256, 0, stream>>>(cnt, part);
    k_scanpartial<<<1, 512, 0, stream>>>(part, poff);
    k_scan3<<<NCHUNKS, 256, 0, stream>>>(cnt, poff, rowptr);

    // --- bucket sort: COO -> staged (bucket-major) -> packed (row-major) ---
    k_initcur<<<2, 256, 0, stream>>>(rowptr, gcur);
    k_bucketA<<<bucketA_blocks, 256, 0, stream>>>(rows, cols, vals, gcur, staged);
    k_bucketB<<<NB, 1024, 0, stream>>>(rowptr, staged, packed);

    // --- x0: bf16 copy + fp32 acc init ---
    k_init0<<<vec_blocks, 256, 0, stream>>>(ue, ie, xb0, acc);

    // --- 3 layers, acc fused, /4 fused into last ---
    k_spmm_csr<0><<<row_blocks, 256, 0, stream>>>(rowptr, packed, xb0, xb1, acc);
    k_spmm_csr<0><<<row_blocks, 256, 0, stream>>>(rowptr, packed, xb1, xb2, acc);
    k_spmm_csr<1><<<row_blocks, 256, 0, stream>>>(rowptr, packed, xb2, (unsigned short*)nullptr, acc);
}